// Round 1
// baseline (66.329 us; speedup 1.0000x reference)
//
#include <hip/hip_runtime.h>

#define THREADS 256
#define PPT 32          // points per thread = N / THREADS
#define KNN 32
#define CAP 1024        // candidate buffer capacity
#define MAXIT 34

constexpr int Bc = 4, Nc = 8192, Sc = 2048, Cch = 64;

__global__ __launch_bounds__(THREADS) void neighbor_group_kernel(
    const float* __restrict__ xyz,      // (B, N, 3)
    const float* __restrict__ new_xyz,  // (B, S, 3)
    const float* __restrict__ feat,     // (B, N, C)
    float* __restrict__ out)
{
  __shared__ unsigned int candDb[CAP];
  __shared__ unsigned int candIdx[CAP];
  __shared__ unsigned int cnt[MAXIT];
  __shared__ unsigned int redmax[4];
  __shared__ unsigned int winIdx[KNN];
  __shared__ unsigned int winDb[KNN];
  __shared__ unsigned int ccount;

  const int tid = threadIdx.x;
  const int q = blockIdx.x;            // 0 .. B*S-1
  const int b = q >> 11;               // / S (S = 2048)

  if (tid < MAXIT) cnt[tid] = 0u;
  if (tid == 0) ccount = 0u;

  const float qx = new_xyz[q * 3 + 0];
  const float qy = new_xyz[q * 3 + 1];
  const float qz = new_xyz[q * 3 + 2];

  const float* xb = xyz + (size_t)b * Nc * 3;

  // --- distances (bit-exact vs numpy: no FMA contraction, IEEE sqrt) ---
  unsigned int keys[PPT];
  unsigned int lmin = 0xFFFFFFFFu;
#pragma unroll
  for (int j = 0; j < PPT; ++j) {
    const int p = tid + j * THREADS;
    const float x = xb[p * 3 + 0];
    const float y = xb[p * 3 + 1];
    const float z = xb[p * 3 + 2];
    const float dx = qx - x, dy = qy - y, dz = qz - z;
    const float s2 = __fadd_rn(__fadd_rn(__fmul_rn(dx, dx), __fmul_rn(dy, dy)),
                               __fmul_rn(dz, dz));
    const float d = __fsqrt_rn(s2);
    const unsigned int kb = __float_as_uint(d);
    keys[j] = kb;
    lmin = min(lmin, kb);
  }

  // --- upper bound: max over per-thread mins (>=256 elements below) ---
  unsigned int wmax = lmin;
#pragma unroll
  for (int m = 32; m >= 1; m >>= 1) {
    wmax = max(wmax, (unsigned int)__shfl_xor((int)wmax, m, 64));
  }
  if ((tid & 63) == 0) redmax[tid >> 6] = wmax;
  __syncthreads();
  const unsigned int ub =
      max(max(redmax[0], redmax[1]), max(redmax[2], redmax[3])) + 1u;

  // --- binary search pivot so that count(keys < piv) in [KNN, CAP] ---
  unsigned int piv;
  {
    unsigned int lo = 0u, hi = ub;
    unsigned int p0 = __float_as_uint(__uint_as_float(ub - 1u) * 0.35f);
    if (!(p0 > lo && p0 < hi)) p0 = lo + ((hi - lo) >> 1);
    piv = p0;
    for (int it = 0; it < MAXIT; ++it) {
      unsigned int local = 0u;
#pragma unroll
      for (int j = 0; j < PPT; ++j) local += (keys[j] < piv) ? 1u : 0u;
#pragma unroll
      for (int m = 32; m >= 1; m >>= 1) local += __shfl_xor(local, m, 64);
      if ((tid & 63) == 0) atomicAdd(&cnt[it], local);
      __syncthreads();
      const unsigned int c = cnt[it];
      if (c >= KNN && c <= CAP) break;           // good pivot
      if (c < KNN) lo = piv; else hi = piv;      // c(lo)<K, c(hi)>=K invariant
      if (hi - lo <= 1u) { piv = hi; break; }    // degenerate: use hi
      piv = lo + ((hi - lo) >> 1);
    }
  }

  // --- compact candidates (keys < piv) to LDS ---
#pragma unroll
  for (int j = 0; j < PPT; ++j) {
    if (keys[j] < piv) {
      const unsigned int pos = atomicAdd(&ccount, 1u);
      if (pos < CAP) {
        candDb[pos]  = keys[j];
        candIdx[pos] = (unsigned int)(tid + j * THREADS);
      }
    }
  }
  __syncthreads();
  const unsigned int Ccnt = min(ccount, (unsigned int)CAP);

  // --- exact rank by (distbits, idx) lexicographic; unique ranks ---
  for (unsigned int t = tid; t < Ccnt; t += THREADS) {
    const unsigned int mdb = candDb[t];
    const unsigned int mix = candIdx[t];
    unsigned int rank = 0u;
    for (unsigned int o = 0; o < Ccnt; ++o) {
      const unsigned int odb = candDb[o];
      const unsigned int oix = candIdx[o];
      rank += (odb < mdb || (odb == mdb && oix < mix)) ? 1u : 0u;
    }
    if (rank < KNN) { winIdx[rank] = mix; winDb[rank] = mdb; }
  }
  __syncthreads();

  // --- outputs (flat concat: nxyz | idxs | nfeat | values), all f32 ---
  float* out_nx = out;                                          // B*S*K*3
  float* out_id = out + (size_t)Bc * Sc * KNN * 3;              // B*S*K
  float* out_nf = out_id + (size_t)Bc * Sc * KNN;               // B*S*K*C
  float* out_sv = out_nf + (size_t)Bc * Sc * KNN * Cch;         // B*S*K

  if (tid < KNN) {
    out_id[(size_t)q * KNN + tid] = (float)winIdx[tid];
    out_sv[(size_t)q * KNN + tid] = __uint_as_float(winDb[tid]);
  }
  if (tid < KNN * 3) {
    const int w = tid / 3, c3 = tid % 3;
    out_nx[((size_t)q * KNN + w) * 3 + c3] =
        xb[(size_t)winIdx[w] * 3 + c3];
  }
  const float* fb = feat + (size_t)b * Nc * Cch;
#pragma unroll
  for (int r = 0; r < (KNN * Cch) / THREADS; ++r) {   // 8 rounds
    const int flat = tid + r * THREADS;
    const int w = flat >> 6;          // / C
    const int c2 = flat & 63;         // % C
    out_nf[((size_t)q * KNN + w) * Cch + c2] =
        fb[(size_t)winIdx[w] * Cch + c2];
  }
}

extern "C" void kernel_launch(void* const* d_in, const int* in_sizes, int n_in,
                              void* d_out, int out_size, void* d_ws, size_t ws_size,
                              hipStream_t stream) {
  const float* xyz     = (const float*)d_in[0];
  const float* new_xyz = (const float*)d_in[1];
  const float* feat    = (const float*)d_in[2];
  float* out = (float*)d_out;

  const int grid = Bc * Sc;  // 8192 queries
  neighbor_group_kernel<<<grid, THREADS, 0, stream>>>(xyz, new_xyz, feat, out);
}